// Round 16
// baseline (1645.821 us; speedup 1.0000x reference)
//
#include <hip/hip_runtime.h>
#include <stdint.h>

#define T_SEQ 128
#define B_SZ  32
#define H_DIM 1024
#define E_DIM 512
#define V_DIM 32000
#define SOS_TOK 1
#define NPROD 16      // producer blocks (8 per batch group, 128 cols each)
#define NCONS 448
#define NTILES 8000   // 32 mtp x 250 nt

typedef float v4f __attribute__((ext_vector_type(4)));
typedef short short8 __attribute__((ext_vector_type(8)));

// RNE float->bf16
__device__ inline uint16_t f2bf(float x) {
    uint32_t u = __float_as_uint(x);
    uint32_t r = (u + 0x7fffu + ((u >> 16) & 1u)) >> 16;
    return (uint16_t)r;
}
__device__ inline uint32_t pack2(float a, float b) {
    return (uint32_t)f2bf(a) | ((uint32_t)f2bf(b) << 16);
}

// async global->LDS, 16B per lane. lds base must be wave-uniform.
__device__ inline void gload16(const void* g, void* l) {
    __builtin_amdgcn_global_load_lds(
        (const __attribute__((address_space(1))) uint32_t*)g,
        (__attribute__((address_space(3))) uint32_t*)l, 16, 0, 0);
}

// ---------------------------------------------------------------------------
// kconv: fp32 -> bf16, 2048 elements per block
// ---------------------------------------------------------------------------
__global__ __launch_bounds__(256) void kconv(const float* __restrict__ W,
                                             uint16_t* __restrict__ Wb) {
    size_t i = ((size_t)blockIdx.x * 256 + threadIdx.x) * 8;
    float4 a = *(const float4*)&W[i];
    float4 c = *(const float4*)&W[i + 4];
    uint4 p;
    p.x = pack2(a.x, a.y); p.y = pack2(a.z, a.w);
    p.z = pack2(c.x, c.y); p.w = pack2(c.z, c.w);
    *(uint4*)&Wb[i] = p;
}

// ---------------------------------------------------------------------------
// kxwm: xW[t*B+b][n] = emb[tok(b,t)] . Wih[n] + bih[n] + bhh[n]   (bf16 MFMA)
// ---------------------------------------------------------------------------
__global__ __launch_bounds__(256) void kxwm(const int* __restrict__ target,
                                            const float* __restrict__ emb,
                                            const float* __restrict__ Wih,
                                            const float* __restrict__ bih,
                                            const float* __restrict__ bhh,
                                            float* __restrict__ xW) {
    __shared__ __align__(16) uint16_t As[128 * 32];
    __shared__ __align__(16) uint16_t Bs[128 * 32];
    __shared__ int toks[128];
    int m0 = blockIdx.x * 128, n0 = blockIdx.y * 128;
    int tid = threadIdx.x;
    if (tid < 128) {
        int row = m0 + tid;
        int t = row & (T_SEQ - 1);
        toks[tid] = (t == 0) ? SOS_TOK : target[row];
    }
    __syncthreads();

    v4f acc[4][4] = {};
    int lane = tid & 63, wv = tid >> 6, wm = wv >> 1, wn = wv & 1;
    int ar = lane & 15, ko = (lane >> 4) * 8;

    for (int k0 = 0; k0 < E_DIM; k0 += 32) {
#pragma unroll
        for (int l = 0; l < 2; ++l) {
            int c = tid + l * 256;
            int r = c >> 2, ko8 = (c & 3) * 8;
            const float* asrc = &emb[(size_t)toks[r] * E_DIM + k0 + ko8];
            float4 x = *(const float4*)asrc;
            float4 y = *(const float4*)(asrc + 4);
            uint4 p;
            p.x = pack2(x.x, x.y); p.y = pack2(x.z, x.w);
            p.z = pack2(y.x, y.y); p.w = pack2(y.z, y.w);
            *(uint4*)&As[r * 32 + ko8] = p;
            const float* bsrc = &Wih[(size_t)(n0 + r) * E_DIM + k0 + ko8];
            float4 u = *(const float4*)bsrc;
            float4 v = *(const float4*)(bsrc + 4);
            uint4 q;
            q.x = pack2(u.x, u.y); q.y = pack2(u.z, u.w);
            q.z = pack2(v.x, v.y); q.w = pack2(v.z, v.w);
            *(uint4*)&Bs[r * 32 + ko8] = q;
        }
        __syncthreads();

        short8 a[4], bfr[4];
#pragma unroll
        for (int i = 0; i < 4; ++i)
            a[i] = *(const short8*)&As[(wm * 64 + i * 16 + ar) * 32 + ko];
#pragma unroll
        for (int jj = 0; jj < 4; ++jj)
            bfr[jj] = *(const short8*)&Bs[(wn * 64 + jj * 16 + ar) * 32 + ko];
#pragma unroll
        for (int i = 0; i < 4; ++i)
#pragma unroll
            for (int jj = 0; jj < 4; ++jj)
                acc[i][jj] = __builtin_amdgcn_mfma_f32_16x16x32_bf16(
                    a[i], bfr[jj], acc[i][jj], 0, 0, 0);
        __syncthreads();
    }

    int fr = lane & 15, fq = lane >> 4;
#pragma unroll
    for (int jj = 0; jj < 4; ++jj) {
        int col = n0 + wn * 64 + jj * 16 + fr;
        float bias = bih[col] + bhh[col];
#pragma unroll
        for (int i = 0; i < 4; ++i) {
            int row = m0 + wm * 64 + i * 16 + fq * 4;
#pragma unroll
            for (int q = 0; q < 4; ++q) {
                int m = row + q;                 // = b*T + t
                int b = m >> 7, t = m & (T_SEQ - 1);
                xW[((size_t)t * B_SZ + b) * H_DIM + col] = acc[i][jj][q] + bias;
            }
        }
    }
}

// ---------------------------------------------------------------------------
// kfused: 464 blocks x 256 thr.
//  blocks 0..15   : producers, FAN-IN 8: block (bg=blk&1, ngg=blk>>1 in
//                   0..7) owns 128 cols = 4 waves x two 16-col tiles.
//                   A-frags loaded once, used by both col-tiles. Barrier:
//                   release own flag every step; wait on the 8 flags of own
//                   batch group (was 16). Otherwise R13/R15 body verbatim.
//  blocks 16..463 : consumers VERBATIM R13 (proxy gate; verify now 16 flags).
// ---------------------------------------------------------------------------
template <bool BBF>
__global__ __launch_bounds__(256) void kfused(const uint16_t* __restrict__ hbInit,
                                              const uint16_t* __restrict__ WbHH,
                                              const float* __restrict__ xW,
                                              uint16_t* __restrict__ Hb,
                                              uint32_t* __restrict__ flags,
                                              const void* __restrict__ Bop,
                                              const float* __restrict__ bout,
                                              float* __restrict__ out) {
    __shared__ __align__(16) uint16_t As[128 * 32];
    __shared__ __align__(16) uint16_t Bs[128 * 32];
    int tid = threadIdx.x;
    int lane = tid & 63;

    if (blockIdx.x < NPROD) {
        // ---------------- producer: recurrence, fan-in 8 ----------------
        __builtin_amdgcn_s_setprio(1);
        int blk = blockIdx.x;
        int bg = blk & 1, ngg = blk >> 1;     // ngg 0..7
        int w = tid >> 6;
        int ncol0 = ngg * 128 + w * 32;       // wave owns cols [ncol0, ncol0+32)
        int lr = lane & 15, lk = (lane >> 4) * 8;

        short8 wf0[32], wf1[32];
        const uint16_t* wr0 = WbHH + (size_t)(ncol0 + lr) * H_DIM + lk;
        const uint16_t* wr1 = WbHH + (size_t)(ncol0 + 16 + lr) * H_DIM + lk;
#pragma unroll
        for (int kt = 0; kt < 32; ++kt) {
            wf0[kt] = *(const short8*)(wr0 + (size_t)kt * 32);
            wf1[kt] = *(const short8*)(wr1 + (size_t)kt * 32);
        }

        int brow = bg * 16 + lr;
        int eb = bg * 16 + (lane >> 4) * 4;
        int en0 = ncol0 + lr, en1 = en0 + 16;
        uint32_t* Hb32 = (uint32_t*)Hb;
        uint32_t* myflag = flags + (size_t)(bg * 8 + ngg) * 32;
        const uint32_t* grpflags = flags + (size_t)(bg * 8) * 32;

        for (int t = 0; t < T_SEQ; ++t) {
            const uint16_t* arow =
                ((t == 0) ? hbInit : Hb + (size_t)(t - 1) * B_SZ * H_DIM)
                + (size_t)brow * H_DIM + lk;

            float xv0[4], xv1[4];
#pragma unroll
            for (int q = 0; q < 4; ++q) {
                size_t rbase = ((size_t)t * B_SZ + eb + q) * H_DIM;
                xv0[q] = xW[rbase + en0];
                xv1[q] = xW[rbase + en1];
            }

            v4f a0_0 = {0.f,0.f,0.f,0.f}, a0_1 = {0.f,0.f,0.f,0.f};
            v4f a0_2 = {0.f,0.f,0.f,0.f}, a0_3 = {0.f,0.f,0.f,0.f};
            v4f a1_0 = {0.f,0.f,0.f,0.f}, a1_1 = {0.f,0.f,0.f,0.f};
            v4f a1_2 = {0.f,0.f,0.f,0.f}, a1_3 = {0.f,0.f,0.f,0.f};
            short8 af0[16], af1[16];
#pragma unroll
            for (int kt = 0; kt < 16; ++kt)
                af0[kt] = *(const short8*)(arow + (size_t)kt * 32);
#pragma unroll
            for (int kt = 0; kt < 16; ++kt)
                af1[kt] = *(const short8*)(arow + 512 + (size_t)kt * 32);
#pragma unroll
            for (int kt = 0; kt < 16; ++kt) {
                v4f* p0 = (kt & 3) == 0 ? &a0_0 : (kt & 3) == 1 ? &a0_1
                        : (kt & 3) == 2 ? &a0_2 : &a0_3;
                v4f* p1 = (kt & 3) == 0 ? &a1_0 : (kt & 3) == 1 ? &a1_1
                        : (kt & 3) == 2 ? &a1_2 : &a1_3;
                *p0 = __builtin_amdgcn_mfma_f32_16x16x32_bf16(af0[kt], wf0[kt], *p0, 0, 0, 0);
                *p1 = __builtin_amdgcn_mfma_f32_16x16x32_bf16(af0[kt], wf1[kt], *p1, 0, 0, 0);
            }
#pragma unroll
            for (int kt = 0; kt < 16; ++kt) {
                v4f* p0 = (kt & 3) == 0 ? &a0_0 : (kt & 3) == 1 ? &a0_1
                        : (kt & 3) == 2 ? &a0_2 : &a0_3;
                v4f* p1 = (kt & 3) == 0 ? &a1_0 : (kt & 3) == 1 ? &a1_1
                        : (kt & 3) == 2 ? &a1_2 : &a1_3;
                *p0 = __builtin_amdgcn_mfma_f32_16x16x32_bf16(af1[kt], wf0[16 + kt], *p0, 0, 0, 0);
                *p1 = __builtin_amdgcn_mfma_f32_16x16x32_bf16(af1[kt], wf1[16 + kt], *p1, 0, 0, 0);
            }
            v4f acc0 = (a0_0 + a0_1) + (a0_2 + a0_3);
            v4f acc1 = (a1_0 + a1_1) + (a1_2 + a1_3);

            float hv0[4], hv1[4];
#pragma unroll
            for (int q = 0; q < 4; ++q) {
                hv0[q] = tanhf(acc0[q] + xv0[q]);
                hv1[q] = tanhf(acc1[q] + xv1[q]);
            }

            // publish write-through, col-pair packed (2 stores/lane/tile)
#pragma unroll
            for (int q = 0; q < 4; ++q) {
                float pv0 = __shfl_xor(hv0[q], 1);
                float pv1 = __shfl_xor(hv1[q], 1);
                bool mine = ((lane & 1) == 0) ? (q < 2) : (q >= 2);
                if (mine) {
                    size_t rbase = ((size_t)t * B_SZ + eb + q) * H_DIM;
                    uint32_t w0 = (lane & 1) ? pack2(pv0, hv0[q]) : pack2(hv0[q], pv0);
                    uint32_t w1 = (lane & 1) ? pack2(pv1, hv1[q]) : pack2(hv1[q], pv1);
                    __hip_atomic_store(&Hb32[(rbase + (size_t)(en0 & ~1)) >> 1], w0,
                                       __ATOMIC_RELAXED, __HIP_MEMORY_SCOPE_AGENT);
                    __hip_atomic_store(&Hb32[(rbase + (size_t)(en1 & ~1)) >> 1], w1,
                                       __ATOMIC_RELAXED, __HIP_MEMORY_SCOPE_AGENT);
                }
            }

            __syncthreads();   // drain all waves' stores before arrival
            if (tid == 0)
                __hip_atomic_store(myflag, (uint32_t)(t + 1), __ATOMIC_RELEASE,
                                   __HIP_MEMORY_SCOPE_AGENT);
            if (t < T_SEQ - 1) {
                if (tid < 8) {
                    const uint32_t* f = grpflags + (size_t)tid * 32;
                    while (__hip_atomic_load(f, __ATOMIC_RELAXED,
                                             __HIP_MEMORY_SCOPE_AGENT) <= (uint32_t)t)
                        __builtin_amdgcn_s_sleep(2);
                }
                if (tid == 0)
                    (void)__hip_atomic_load(myflag, __ATOMIC_ACQUIRE,
                                            __HIP_MEMORY_SCOPE_AGENT);
                __syncthreads();
            }
        }
    } else {
        // ---------------- consumer: decode GEMM (R13, 16 flags) -----------
        int c = blockIdx.x - NPROD;
        int wv = tid >> 6, wm = wv >> 1, wn = wv & 1;
        int ar = lane & 15, ko = (lane >> 4) * 8;
        int sx = BBF ? (((ar >> 1) & 3) << 3) : 0;
        int fr = lane & 15, fq = lane >> 4;
        int gate_seen = 0;
        const uint32_t* proxyf = flags + (size_t)(c & 15) * 32;

        const uint16_t* Bb = (const uint16_t*)Bop;
        const float*    Bf = (const float*)Bop;

        for (int g = c; g < NTILES; g += NCONS) {
            int mtp = g / 250, nt = g - mtp * 250;
            int need = 4 * mtp + 4;
            if (need > gate_seen) {
                if (tid == 0) {
                    while (__hip_atomic_load(proxyf, __ATOMIC_RELAXED,
                                             __HIP_MEMORY_SCOPE_AGENT) < (uint32_t)need)
                        __builtin_amdgcn_s_sleep(32);
                }
                __syncthreads();
                if (tid < 16) {
                    const uint32_t* f = flags + (size_t)tid * 32;
                    while (__hip_atomic_load(f, __ATOMIC_RELAXED,
                                             __HIP_MEMORY_SCOPE_AGENT) < (uint32_t)need)
                        __builtin_amdgcn_s_sleep(2);
                }
                __syncthreads();
                if (tid == 0)
                    (void)__hip_atomic_load(flags, __ATOMIC_ACQUIRE,
                                            __HIP_MEMORY_SCOPE_AGENT);
                __syncthreads();
                gate_seen = need;
            }

            int m0 = mtp * 128, n0 = nt * 128;
            v4f acc[4][4] = {};

            for (int k0 = 0; k0 < H_DIM; k0 += 32) {
                int wb = tid & ~63;
                if constexpr (BBF) {
#pragma unroll
                    for (int l = 0; l < 2; ++l) {
                        int cc = tid + l * 256;
                        int r = cc >> 2;
                        int gsw = ((cc & 3) ^ ((cc >> 3) & 3)) * 8;
                        gload16(&Hb[(size_t)(m0 + r) * H_DIM + k0 + gsw],
                                (char*)As + (size_t)(wb + l * 256) * 16);
                        gload16(&Bb[(size_t)(n0 + r) * H_DIM + k0 + gsw],
                                (char*)Bs + (size_t)(wb + l * 256) * 16);
                    }
                } else {
#pragma unroll
                    for (int l = 0; l < 2; ++l) {
                        int cc = tid + l * 256;
                        int r = cc >> 2, ko8 = (cc & 3) * 8;
                        gload16(&Hb[(size_t)(m0 + r) * H_DIM + k0 + ko8],
                                (char*)As + (size_t)(wb + l * 256) * 16);
                        const float* src = &Bf[(size_t)(n0 + r) * H_DIM + k0 + ko8];
                        float4 x = *(const float4*)src;
                        float4 y = *(const float4*)(src + 4);
                        uint4 p;
                        p.x = pack2(x.x, x.y); p.y = pack2(x.z, x.w);
                        p.z = pack2(y.x, y.y); p.w = pack2(y.z, y.w);
                        *(uint4*)&Bs[r * 32 + ko8] = p;
                    }
                }
                __syncthreads();

                short8 a[4], bfr[4];
#pragma unroll
                for (int i = 0; i < 4; ++i)
                    a[i] = *(const short8*)&As[(wm * 64 + i * 16 + ar) * 32 + (ko ^ sx)];
#pragma unroll
                for (int jj = 0; jj < 4; ++jj)
                    bfr[jj] = *(const short8*)&Bs[(wn * 64 + jj * 16 + ar) * 32 + (ko ^ sx)];
#pragma unroll
                for (int i = 0; i < 4; ++i)
#pragma unroll
                    for (int jj = 0; jj < 4; ++jj)
                        acc[i][jj] = __builtin_amdgcn_mfma_f32_16x16x32_bf16(
                            a[i], bfr[jj], acc[i][jj], 0, 0, 0);
                __syncthreads();
            }

#pragma unroll
            for (int jj = 0; jj < 4; ++jj) {
                int col = n0 + wn * 64 + jj * 16 + fr;
                float bo = bout[col];
#pragma unroll
                for (int i = 0; i < 4; ++i) {
                    int rbase = wm * 64 + i * 16 + fq * 4;
#pragma unroll
                    for (int q = 0; q < 4; ++q) {
                        int mp = m0 + rbase + q;          // row in [t][b] space
                        int tt = mp >> 5, bb = mp & 31;
                        out[((size_t)bb * T_SEQ + tt) * V_DIM + col] =
                            acc[i][jj][q] + bo;
                    }
                }
            }
        }
    }
}

// ---------------------------------------------------------------------------
extern "C" void kernel_launch(void* const* d_in, const int* in_sizes, int n_in,
                              void* d_out, int out_size, void* d_ws, size_t ws_size,
                              hipStream_t stream) {
    const int*   target = (const int*)d_in[0];
    const float* h0     = (const float*)d_in[1];
    const float* emb    = (const float*)d_in[2];
    const float* Wih    = (const float*)d_in[3];
    const float* bih    = (const float*)d_in[4];
    const float* Whh    = (const float*)d_in[5];
    const float* bhh    = (const float*)d_in[6];
    const float* Wout   = (const float*)d_in[7];
    const float* bout   = (const float*)d_in[8];
    float* out = (float*)d_out;

    char* ws = (char*)d_ws;
    // ws layout (bytes):
    float*    xW     = (float*)(ws);                    // 16,777,216
    uint16_t* WbHH   = (uint16_t*)(ws + 16777216);      //  2,097,152
    uint16_t* hbInit = (uint16_t*)(ws + 18874368);      //     65,536
    uint32_t* flags  = (uint32_t*)(ws + 18939904);      //      4,096
    uint16_t* Hb     = (uint16_t*)(ws + 18944000);      //  8,388,608 -> 27,332,608
    uint16_t* WbOut  = (uint16_t*)(ws + 27332608);      // 65,536,000 -> 92,868,608
    const bool wbok = ws_size >= 92868608ull;           // R1 evidence: ws >= 95.2MB

    kconv<<<512, 256, 0, stream>>>(Whh, WbHH);       // 1,048,576 elts
    kconv<<<16, 256, 0, stream>>>(h0, hbInit);       //    32,768 elts
    kxwm<<<dim3(32, 8), 256, 0, stream>>>(target, emb, Wih, bih, bhh, xW);
    hipMemsetAsync(flags, 0, 4096, stream);

    if (wbok) {
        kconv<<<16000, 256, 0, stream>>>(Wout, WbOut);   // 32,768,000 elts
        kfused<true><<<NPROD + NCONS, 256, 0, stream>>>(hbInit, WbHH, xW, Hb, flags,
                                                        (const void*)WbOut, bout, out);
    } else {
        kfused<false><<<NPROD + NCONS, 256, 0, stream>>>(hbInit, WbHH, xW, Hb, flags,
                                                         (const void*)Wout, bout, out);
    }
}

// Round 17
// 1068.698 us; speedup vs baseline: 1.5400x; 1.5400x over previous
//
#include <hip/hip_runtime.h>
#include <stdint.h>

#define T_SEQ 128
#define B_SZ  32
#define H_DIM 1024
#define E_DIM 512
#define V_DIM 32000
#define SOS_TOK 1
#define NCONS 224     // consumers; grid 32+224 = 256 = #CUs -> ~1 block/CU
#define NTILES 8000   // 32 mtp x 250 nt

typedef float v4f __attribute__((ext_vector_type(4)));
typedef short short8 __attribute__((ext_vector_type(8)));

// RNE float->bf16
__device__ inline uint16_t f2bf(float x) {
    uint32_t u = __float_as_uint(x);
    uint32_t r = (u + 0x7fffu + ((u >> 16) & 1u)) >> 16;
    return (uint16_t)r;
}
__device__ inline uint32_t pack2(float a, float b) {
    return (uint32_t)f2bf(a) | ((uint32_t)f2bf(b) << 16);
}

// async global->LDS, 16B per lane. lds base must be wave-uniform.
__device__ inline void gload16(const void* g, void* l) {
    __builtin_amdgcn_global_load_lds(
        (const __attribute__((address_space(1))) uint32_t*)g,
        (__attribute__((address_space(3))) uint32_t*)l, 16, 0, 0);
}

// ---------------------------------------------------------------------------
// kconv: fp32 -> bf16, 2048 elements per block
// ---------------------------------------------------------------------------
__global__ __launch_bounds__(256) void kconv(const float* __restrict__ W,
                                             uint16_t* __restrict__ Wb) {
    size_t i = ((size_t)blockIdx.x * 256 + threadIdx.x) * 8;
    float4 a = *(const float4*)&W[i];
    float4 c = *(const float4*)&W[i + 4];
    uint4 p;
    p.x = pack2(a.x, a.y); p.y = pack2(a.z, a.w);
    p.z = pack2(c.x, c.y); p.w = pack2(c.z, c.w);
    *(uint4*)&Wb[i] = p;
}

// ---------------------------------------------------------------------------
// kxwm: xW[t*B+b][n] = emb[tok(b,t)] . Wih[n] + bih[n] + bhh[n]   (bf16 MFMA)
// ---------------------------------------------------------------------------
__global__ __launch_bounds__(256) void kxwm(const int* __restrict__ target,
                                            const float* __restrict__ emb,
                                            const float* __restrict__ Wih,
                                            const float* __restrict__ bih,
                                            const float* __restrict__ bhh,
                                            float* __restrict__ xW) {
    __shared__ __align__(16) uint16_t As[128 * 32];
    __shared__ __align__(16) uint16_t Bs[128 * 32];
    __shared__ int toks[128];
    int m0 = blockIdx.x * 128, n0 = blockIdx.y * 128;
    int tid = threadIdx.x;
    if (tid < 128) {
        int row = m0 + tid;
        int t = row & (T_SEQ - 1);
        toks[tid] = (t == 0) ? SOS_TOK : target[row];
    }
    __syncthreads();

    v4f acc[4][4] = {};
    int lane = tid & 63, wv = tid >> 6, wm = wv >> 1, wn = wv & 1;
    int ar = lane & 15, ko = (lane >> 4) * 8;

    for (int k0 = 0; k0 < E_DIM; k0 += 32) {
#pragma unroll
        for (int l = 0; l < 2; ++l) {
            int c = tid + l * 256;
            int r = c >> 2, ko8 = (c & 3) * 8;
            const float* asrc = &emb[(size_t)toks[r] * E_DIM + k0 + ko8];
            float4 x = *(const float4*)asrc;
            float4 y = *(const float4*)(asrc + 4);
            uint4 p;
            p.x = pack2(x.x, x.y); p.y = pack2(x.z, x.w);
            p.z = pack2(y.x, y.y); p.w = pack2(y.z, y.w);
            *(uint4*)&As[r * 32 + ko8] = p;
            const float* bsrc = &Wih[(size_t)(n0 + r) * E_DIM + k0 + ko8];
            float4 u = *(const float4*)bsrc;
            float4 v = *(const float4*)(bsrc + 4);
            uint4 q;
            q.x = pack2(u.x, u.y); q.y = pack2(u.z, u.w);
            q.z = pack2(v.x, v.y); q.w = pack2(v.z, v.w);
            *(uint4*)&Bs[r * 32 + ko8] = q;
        }
        __syncthreads();

        short8 a[4], bfr[4];
#pragma unroll
        for (int i = 0; i < 4; ++i)
            a[i] = *(const short8*)&As[(wm * 64 + i * 16 + ar) * 32 + ko];
#pragma unroll
        for (int jj = 0; jj < 4; ++jj)
            bfr[jj] = *(const short8*)&Bs[(wn * 64 + jj * 16 + ar) * 32 + ko];
#pragma unroll
        for (int i = 0; i < 4; ++i)
#pragma unroll
            for (int jj = 0; jj < 4; ++jj)
                acc[i][jj] = __builtin_amdgcn_mfma_f32_16x16x32_bf16(
                    a[i], bfr[jj], acc[i][jj], 0, 0, 0);
        __syncthreads();
    }

    int fr = lane & 15, fq = lane >> 4;
#pragma unroll
    for (int jj = 0; jj < 4; ++jj) {
        int col = n0 + wn * 64 + jj * 16 + fr;
        float bias = bih[col] + bhh[col];
#pragma unroll
        for (int i = 0; i < 4; ++i) {
            int row = m0 + wm * 64 + i * 16 + fq * 4;
#pragma unroll
            for (int q = 0; q < 4; ++q) {
                int m = row + q;                 // = b*T + t
                int b = m >> 7, t = m & (T_SEQ - 1);
                xW[((size_t)t * B_SZ + b) * H_DIM + col] = acc[i][jj][q] + bias;
            }
        }
    }
}

// ---------------------------------------------------------------------------
// kfused: 256 blocks x 256 thr — VERBATIM R15 except NCONS 448 -> 224 so the
// grid equals the CU count: producers get (near-)dedicated CUs, isolating
// the intra-CU co-residency interference variable.
//  blocks 0..31  : producers (R13/R15 body: reg-resident W frags, af0/af1
//                  preload, write-through publish, tanhf, distributed-flag
//                  barrier, setprio(1)).
//  blocks 32..255: consumers (R13 proxy gate; g = c + k*224).
// ---------------------------------------------------------------------------
template <bool BBF>
__global__ __launch_bounds__(256) void kfused(const uint16_t* __restrict__ hbInit,
                                              const uint16_t* __restrict__ WbHH,
                                              const float* __restrict__ xW,
                                              uint16_t* __restrict__ Hb,
                                              uint32_t* __restrict__ flags,
                                              const void* __restrict__ Bop,
                                              const float* __restrict__ bout,
                                              float* __restrict__ out) {
    __shared__ __align__(16) uint16_t As[128 * 32];
    __shared__ __align__(16) uint16_t Bs[128 * 32];
    int tid = threadIdx.x;
    int lane = tid & 63;

    if (blockIdx.x < 32) {
        // ---------------- producer: recurrence (R15 body, verbatim) -------
        __builtin_amdgcn_s_setprio(1);
        int blk = blockIdx.x;
        int bg = blk & 1, ngg = blk >> 1;
        int w = tid >> 6;
        int ncol0 = ngg * 64 + w * 16;
        int lr = lane & 15, lk = (lane >> 4) * 8;

        short8 wf[32];
        const uint16_t* wrow = WbHH + (size_t)(ncol0 + lr) * H_DIM + lk;
#pragma unroll
        for (int kt = 0; kt < 32; ++kt)
            wf[kt] = *(const short8*)(wrow + (size_t)kt * 32);

        int brow = bg * 16 + lr;
        int eb = bg * 16 + (lane >> 4) * 4;
        int en = ncol0 + lr;
        uint32_t* Hb32 = (uint32_t*)Hb;
        uint32_t* myflag = flags + (size_t)(bg * 16 + ngg) * 32;
        const uint32_t* grpflags = flags + (size_t)(bg * 16) * 32;

        for (int t = 0; t < T_SEQ; ++t) {
            const uint16_t* arow =
                ((t == 0) ? hbInit : Hb + (size_t)(t - 1) * B_SZ * H_DIM)
                + (size_t)brow * H_DIM + lk;

            float xv[4];
#pragma unroll
            for (int q = 0; q < 4; ++q)
                xv[q] = xW[((size_t)t * B_SZ + eb + q) * H_DIM + en];

            v4f ac0 = {0.f,0.f,0.f,0.f}, ac1 = {0.f,0.f,0.f,0.f};
            v4f ac2 = {0.f,0.f,0.f,0.f}, ac3 = {0.f,0.f,0.f,0.f};
            short8 af0[16], af1[16];
#pragma unroll
            for (int kt = 0; kt < 16; ++kt)
                af0[kt] = *(const short8*)(arow + (size_t)kt * 32);
#pragma unroll
            for (int kt = 0; kt < 16; ++kt)
                af1[kt] = *(const short8*)(arow + 512 + (size_t)kt * 32);
#pragma unroll
            for (int kt = 0; kt < 16; ++kt) {
                v4f* a = (kt & 3) == 0 ? &ac0 : (kt & 3) == 1 ? &ac1
                        : (kt & 3) == 2 ? &ac2 : &ac3;
                *a = __builtin_amdgcn_mfma_f32_16x16x32_bf16(af0[kt], wf[kt], *a, 0, 0, 0);
            }
#pragma unroll
            for (int kt = 0; kt < 16; ++kt) {
                v4f* a = (kt & 3) == 0 ? &ac0 : (kt & 3) == 1 ? &ac1
                        : (kt & 3) == 2 ? &ac2 : &ac3;
                *a = __builtin_amdgcn_mfma_f32_16x16x32_bf16(af1[kt], wf[16 + kt], *a, 0, 0, 0);
            }
            v4f acc = (ac0 + ac1) + (ac2 + ac3);

            float hv[4];
#pragma unroll
            for (int q = 0; q < 4; ++q)
                hv[q] = tanhf(acc[q] + xv[q]);

#pragma unroll
            for (int q = 0; q < 4; ++q) {
                float pv = __shfl_xor(hv[q], 1);
                bool mine = ((lane & 1) == 0) ? (q < 2) : (q >= 2);
                if (mine) {
                    uint32_t word = (lane & 1) ? pack2(pv, hv[q]) : pack2(hv[q], pv);
                    size_t i32 = (((size_t)t * B_SZ + eb + q) * H_DIM
                                  + (size_t)(en & ~1)) >> 1;
                    __hip_atomic_store(&Hb32[i32], word, __ATOMIC_RELAXED,
                                       __HIP_MEMORY_SCOPE_AGENT);
                }
            }

            __syncthreads();   // drain all waves' stores before arrival
            if (tid == 0)
                __hip_atomic_store(myflag, (uint32_t)(t + 1), __ATOMIC_RELEASE,
                                   __HIP_MEMORY_SCOPE_AGENT);
            if (t < T_SEQ - 1) {
                if (tid < 16) {
                    const uint32_t* f = grpflags + (size_t)tid * 32;
                    while (__hip_atomic_load(f, __ATOMIC_RELAXED,
                                             __HIP_MEMORY_SCOPE_AGENT) <= (uint32_t)t)
                        __builtin_amdgcn_s_sleep(2);
                }
                if (tid == 0)
                    (void)__hip_atomic_load(myflag, __ATOMIC_ACQUIRE,
                                            __HIP_MEMORY_SCOPE_AGENT);
                __syncthreads();
            }
        }
    } else {
        // ---------------- consumer: decode GEMM (R13, verbatim) -----------
        int c = blockIdx.x - 32;
        int wv = tid >> 6, wm = wv >> 1, wn = wv & 1;
        int ar = lane & 15, ko = (lane >> 4) * 8;
        int sx = BBF ? (((ar >> 1) & 3) << 3) : 0;
        int fr = lane & 15, fq = lane >> 4;
        int gate_seen = 0;
        const uint32_t* proxyf = flags + (size_t)(c & 31) * 32;

        const uint16_t* Bb = (const uint16_t*)Bop;
        const float*    Bf = (const float*)Bop;

        for (int g = c; g < NTILES; g += NCONS) {
            int mtp = g / 250, nt = g - mtp * 250;
            int need = 4 * mtp + 4;
            if (need > gate_seen) {
                if (tid == 0) {
                    while (__hip_atomic_load(proxyf, __ATOMIC_RELAXED,
                                             __HIP_MEMORY_SCOPE_AGENT) < (uint32_t)need)
                        __builtin_amdgcn_s_sleep(32);
                }
                __syncthreads();
                if (tid < 32) {
                    const uint32_t* f = flags + (size_t)tid * 32;
                    while (__hip_atomic_load(f, __ATOMIC_RELAXED,
                                             __HIP_MEMORY_SCOPE_AGENT) < (uint32_t)need)
                        __builtin_amdgcn_s_sleep(2);
                }
                __syncthreads();
                if (tid == 0)
                    (void)__hip_atomic_load(flags, __ATOMIC_ACQUIRE,
                                            __HIP_MEMORY_SCOPE_AGENT);
                __syncthreads();
                gate_seen = need;
            }

            int m0 = mtp * 128, n0 = nt * 128;
            v4f acc[4][4] = {};

            for (int k0 = 0; k0 < H_DIM; k0 += 32) {
                int wb = tid & ~63;
                if constexpr (BBF) {
#pragma unroll
                    for (int l = 0; l < 2; ++l) {
                        int cc = tid + l * 256;
                        int r = cc >> 2;
                        int gsw = ((cc & 3) ^ ((cc >> 3) & 3)) * 8;
                        gload16(&Hb[(size_t)(m0 + r) * H_DIM + k0 + gsw],
                                (char*)As + (size_t)(wb + l * 256) * 16);
                        gload16(&Bb[(size_t)(n0 + r) * H_DIM + k0 + gsw],
                                (char*)Bs + (size_t)(wb + l * 256) * 16);
                    }
                } else {
#pragma unroll
                    for (int l = 0; l < 2; ++l) {
                        int cc = tid + l * 256;
                        int r = cc >> 2, ko8 = (cc & 3) * 8;
                        gload16(&Hb[(size_t)(m0 + r) * H_DIM + k0 + ko8],
                                (char*)As + (size_t)(wb + l * 256) * 16);
                        const float* src = &Bf[(size_t)(n0 + r) * H_DIM + k0 + ko8];
                        float4 x = *(const float4*)src;
                        float4 y = *(const float4*)(src + 4);
                        uint4 p;
                        p.x = pack2(x.x, x.y); p.y = pack2(x.z, x.w);
                        p.z = pack2(y.x, y.y); p.w = pack2(y.z, y.w);
                        *(uint4*)&Bs[r * 32 + ko8] = p;
                    }
                }
                __syncthreads();

                short8 a[4], bfr[4];
#pragma unroll
                for (int i = 0; i < 4; ++i)
                    a[i] = *(const short8*)&As[(wm * 64 + i * 16 + ar) * 32 + (ko ^ sx)];
#pragma unroll
                for (int jj = 0; jj < 4; ++jj)
                    bfr[jj] = *(const short8*)&Bs[(wn * 64 + jj * 16 + ar) * 32 + (ko ^ sx)];
#pragma unroll
                for (int i = 0; i < 4; ++i)
#pragma unroll
                    for (int jj = 0; jj < 4; ++jj)
                        acc[i][jj] = __builtin_amdgcn_mfma_f32_16x16x32_bf16(
                            a[i], bfr[jj], acc[i][jj], 0, 0, 0);
                __syncthreads();
            }

#pragma unroll
            for (int jj = 0; jj < 4; ++jj) {
                int col = n0 + wn * 64 + jj * 16 + fr;
                float bo = bout[col];
#pragma unroll
                for (int i = 0; i < 4; ++i) {
                    int rbase = wm * 64 + i * 16 + fq * 4;
#pragma unroll
                    for (int q = 0; q < 4; ++q) {
                        int mp = m0 + rbase + q;          // row in [t][b] space
                        int tt = mp >> 5, bb = mp & 31;
                        out[((size_t)bb * T_SEQ + tt) * V_DIM + col] =
                            acc[i][jj][q] + bo;
                    }
                }
            }
        }
    }
}

// ---------------------------------------------------------------------------
extern "C" void kernel_launch(void* const* d_in, const int* in_sizes, int n_in,
                              void* d_out, int out_size, void* d_ws, size_t ws_size,
                              hipStream_t stream) {
    const int*   target = (const int*)d_in[0];
    const float* h0     = (const float*)d_in[1];
    const float* emb    = (const float*)d_in[2];
    const float* Wih    = (const float*)d_in[3];
    const float* bih    = (const float*)d_in[4];
    const float* Whh    = (const float*)d_in[5];
    const float* bhh    = (const float*)d_in[6];
    const float* Wout   = (const float*)d_in[7];
    const float* bout   = (const float*)d_in[8];
    float* out = (float*)d_out;

    char* ws = (char*)d_ws;
    // ws layout (bytes):
    float*    xW     = (float*)(ws);                    // 16,777,216
    uint16_t* WbHH   = (uint16_t*)(ws + 16777216);      //  2,097,152
    uint16_t* hbInit = (uint16_t*)(ws + 18874368);      //     65,536
    uint32_t* flags  = (uint32_t*)(ws + 18939904);      //      4,096
    uint16_t* Hb     = (uint16_t*)(ws + 18944000);      //  8,388,608 -> 27,332,608
    uint16_t* WbOut  = (uint16_t*)(ws + 27332608);      // 65,536,000 -> 92,868,608
    const bool wbok = ws_size >= 92868608ull;           // R1 evidence: ws >= 95.2MB

    kconv<<<512, 256, 0, stream>>>(Whh, WbHH);       // 1,048,576 elts
    kconv<<<16, 256, 0, stream>>>(h0, hbInit);       //    32,768 elts
    kxwm<<<dim3(32, 8), 256, 0, stream>>>(target, emb, Wih, bih, bhh, xW);
    hipMemsetAsync(flags, 0, 4096, stream);

    if (wbok) {
        kconv<<<16000, 256, 0, stream>>>(Wout, WbOut);   // 32,768,000 elts
        kfused<true><<<32 + NCONS, 256, 0, stream>>>(hbInit, WbHH, xW, Hb, flags,
                                                     (const void*)WbOut, bout, out);
    } else {
        kfused<false><<<32 + NCONS, 256, 0, stream>>>(hbInit, WbHH, xW, Hb, flags,
                                                      (const void*)Wout, bout, out);
    }
}